// Round 10
// baseline (620.327 us; speedup 1.0000x reference)
//
#include <hip/hip_runtime.h>
#include <hip/hip_bf16.h>

// Problem constants (fixed by setup_inputs)
#define B_   4
#define N_   4096
#define KNN_ 32
#define KK_  64          // 2*k
#define MTOT 1048576     // B*N*KK
#define BN_EPS 1e-3f

typedef unsigned int u32;
typedef unsigned long long u64;
typedef __attribute__((ext_vector_type(8))) short bf16x8;
typedef __attribute__((ext_vector_type(4))) float f32x4;

__device__ __forceinline__ ushort f2bf_bits(float f) {   // RNE, finite inputs only
    u32 b = __float_as_uint(f);
    b += 0x7fffu + ((b >> 16) & 1u);
    return (ushort)(b >> 16);
}

// ---------------------------------------------------------------------------
// K1: dual KNN, atomic-free (r9 structure, unchanged).
// ---------------------------------------------------------------------------
__global__ __launch_bounds__(256, 3) void knn_kernel(
    const float* __restrict__ p1, const float* __restrict__ p2,
    float* __restrict__ feats)
{
    __shared__ float2 cxy[N_];                   // 32 KB
    __shared__ float  cz[N_];                    // 16 KB

    const int tid  = threadIdx.x;
    const int wave = tid >> 6, lane = tid & 63;
    const int pb    = blockIdx.x / 96;           // 0..7
    const int chunk = blockIdx.x % 96;
    const int pr = pb >> 2, b = pb & 3;
    const int start = (chunk * 4096) / 96;
    const int end   = ((chunk + 1) * 4096) / 96;

    const float* srcb = (pr ? p2 : p1) + (size_t)b * 3 * N_;
    for (int n = tid; n < N_; n += 256) {
        float x = srcb[n], y = srcb[N_ + n], z = srcb[2*N_ + n];
        cxy[n] = make_float2(x, y);
        cz[n]  = z;
    }
    __syncthreads();

    const float* p1b = p1 + (size_t)b * 3 * N_;
    const u64 below = (1ull << lane) - 1ull;

    for (int n = start + wave; n < end; n += 4) {
        float qx, qy, qz;
        if (pr == 0) { float2 q = cxy[n]; qx = q.x; qy = q.y; qz = cz[n]; }
        else         { qx = p1b[n]; qy = p1b[N_ + n]; qz = p1b[2*N_ + n]; }
        const float s1 = fmaf(qx, qx, fmaf(qy, qy, qz*qz));

        u32 keys[64];
        u32 a0 = 0xFFFFFFFFu, a1 = 0xFFFFFFFFu, a2 = 0xFFFFFFFFu, a3 = 0xFFFFFFFFu;
        u32 b0 = 0xFFFFFFFFu, b1 = 0xFFFFFFFFu, b2 = 0xFFFFFFFFu, b3 = 0xFFFFFFFFu;
        #pragma unroll
        for (int j = 0; j < 32; ++j) {
            {
                float2 cA = cxy[j * 64 + lane];
                float  zA = cz[j * 64 + lane];
                float cw  = fmaf(cA.x, cA.x, fmaf(cA.y, cA.y, zA*zA));
                float dot = fmaf(qx, cA.x, fmaf(qy, cA.y, qz * zA));
                float d2  = fmaf(-2.0f, dot, s1 + cw);
                u32 u = __float_as_uint(d2);
                u32 key = u ^ (u32)(((int)u >> 31) | 0x80000000);
                keys[j] = key;
                a3 = min(a3, key);
                u32 t;
                t = min(a2, a3); a3 = max(a2, a3); a2 = t;
                t = min(a1, a2); a2 = max(a1, a2); a1 = t;
                t = min(a0, a1); a1 = max(a0, a1); a0 = t;
            }
            {
                float2 cB = cxy[(j + 32) * 64 + lane];
                float  zB = cz[(j + 32) * 64 + lane];
                float cw  = fmaf(cB.x, cB.x, fmaf(cB.y, cB.y, zB*zB));
                float dot = fmaf(qx, cB.x, fmaf(qy, cB.y, qz * zB));
                float d2  = fmaf(-2.0f, dot, s1 + cw);
                u32 u = __float_as_uint(d2);
                u32 key = u ^ (u32)(((int)u >> 31) | 0x80000000);
                keys[j + 32] = key;
                b3 = min(b3, key);
                u32 t;
                t = min(b2, b3); b3 = max(b2, b3); b2 = t;
                t = min(b1, b2); b2 = max(b1, b2); b1 = t;
                t = min(b0, b1); b1 = max(b0, b1); b0 = t;
            }
        }
        u32 k0 = a0, k1 = a1, k2 = a2, k3 = a3;
        #pragma unroll
        for (int m = 0; m < 4; ++m) {
            u32 x = (m == 0) ? b0 : (m == 1) ? b1 : (m == 2) ? b2 : b3;
            k3 = min(k3, x);
            u32 t;
            t = min(k2, k3); k3 = max(k2, k3); k2 = t;
            t = min(k1, k2); k2 = max(k1, k2); k1 = t;
            t = min(k0, k1); k1 = max(k0, k1); k0 = t;
        }

        u32 mn = k0, mx = k3;
        #pragma unroll
        for (int off = 1; off < 64; off <<= 1) {
            mn = min(mn, (u32)__shfl_xor((int)mn, off, 64));
            mx = max(mx, (u32)__shfl_xor((int)mx, off, 64));
        }
        u32 lo = mn, hi = mx;
        while (lo < hi) {
            u32 mid = lo + ((hi - lo) >> 1);
            int c = __popcll(__ballot(k0 <= mid)) + __popcll(__ballot(k1 <= mid))
                  + __popcll(__ballot(k2 <= mid)) + __popcll(__ballot(k3 <= mid));
            if (c >= 32) hi = mid; else lo = mid + 1;
        }
        u32 T = lo;

        int nl;
        if (__ballot(k3 <= T) == 0ull) {
            nl = __popcll(__ballot(k0 < T)) + __popcll(__ballot(k1 < T))
               + __popcll(__ballot(k2 < T)) + __popcll(__ballot(k3 < T));
        } else {
            nl = 0;
            #pragma unroll
            for (int j = 0; j < 64; ++j) nl += __popcll(__ballot(keys[j] < T));
            if (nl > 31) {
                lo = 0u; hi = T;
                while (lo < hi) {
                    u32 mid = lo + ((hi - lo) >> 1);
                    int c = 0;
                    #pragma unroll
                    for (int j = 0; j < 64; ++j) c += __popcll(__ballot(keys[j] <= mid));
                    if (c >= 32) hi = mid; else lo = mid + 1;
                }
                T = lo;
                nl = 0;
                #pragma unroll
                for (int j = 0; j < 64; ++j) nl += __popcll(__ballot(keys[j] < T));
            }
        }
        const int need_eq = 32 - nl;

        float* fout = feats + ((size_t)(b * N_ + n) * KK_ + pr * KNN_) * 4;
        int base = 0, eq_seen = 0;
        #pragma unroll
        for (int j = 0; j < 64; ++j) {
            u32 key = keys[j];
            bool lt = key < T;
            bool eq = key == T;
            u64 mlt = __ballot(lt);
            u64 meq = __ballot(eq);
            if (mlt | meq) {
                int slot = -1;
                if (lt) slot = base + __popcll(mlt & below);
                else if (eq) {
                    int es = eq_seen + __popcll(meq & below);
                    if (es < need_eq) slot = nl + es;
                }
                if (slot >= 0) {
                    float2 cx2 = cxy[j * 64 + lane];
                    float  cz1 = cz[j * 64 + lane];
                    float rx = cx2.x - qx, ry = cx2.y - qy, rz = cz1 - qz;
                    float dist = sqrtf(fmaf(rx, rx, fmaf(ry, ry, rz*rz)));
                    *(float4*)(fout + slot * 4) = make_float4(rx, ry, rz, dist);
                }
                base    += __popcll(mlt);
                eq_seen += __popcll(meq);
            }
        }
    }
}

// ---------------------------------------------------------------------------
// K2: 14 global moments of feats (padded counters, one cacheline each).
// ---------------------------------------------------------------------------
__global__ __launch_bounds__(256) void moments_kernel(
    const float4* __restrict__ feats4, float* __restrict__ mom)
{
    __shared__ float part[4][14];
    const int tid = threadIdx.x, lane = tid & 63, wv = tid >> 6;
    float a[14];
    #pragma unroll
    for (int s = 0; s < 14; ++s) a[s] = 0.f;
    for (int idx = blockIdx.x * 256 + tid; idx < MTOT; idx += 256 * 256) {
        float4 f = feats4[idx];
        a[0] += f.x; a[1] += f.y; a[2] += f.z; a[3] += f.w;
        a[4]  = fmaf(f.x, f.x, a[4]);  a[5]  = fmaf(f.x, f.y, a[5]);
        a[6]  = fmaf(f.x, f.z, a[6]);  a[7]  = fmaf(f.x, f.w, a[7]);
        a[8]  = fmaf(f.y, f.y, a[8]);  a[9]  = fmaf(f.y, f.z, a[9]);
        a[10] = fmaf(f.y, f.w, a[10]); a[11] = fmaf(f.z, f.z, a[11]);
        a[12] = fmaf(f.z, f.w, a[12]); a[13] = fmaf(f.w, f.w, a[13]);
    }
    #pragma unroll
    for (int s = 0; s < 14; ++s) {
        #pragma unroll
        for (int off = 1; off < 64; off <<= 1) a[s] += __shfl_xor(a[s], off, 64);
    }
    if (lane == 0) {
        #pragma unroll
        for (int s = 0; s < 14; ++s) part[wv][s] = a[s];
    }
    __syncthreads();
    if (tid < 14) {
        float v = part[0][tid] + part[1][tid] + part[2][tid] + part[3][tid];
        atomicAdd(&mom[tid * 16], v);
    }
}

// ---------------------------------------------------------------------------
// Shared device helpers for the conv passes.
// w1L/c1L: folded conv1+bn1 constants, computed into LDS by tid<64.
// ---------------------------------------------------------------------------
__device__ __forceinline__ void build_w1L(
    int tid, const float* __restrict__ W1, const float* __restrict__ g1,
    const float* __restrict__ be1, const float* __restrict__ mom,
    float4* w1L, float* c1L)
{
    if (tid < 64) {
        const float invM = 1.0f / MTOT;
        int ci = tid;
        float w0 = W1[ci*4+0], w1 = W1[ci*4+1], w2 = W1[ci*4+2], w3 = W1[ci*4+3];
        float meanf = (w0*mom[0] + w1*mom[16] + w2*mom[32] + w3*mom[48]) * invM;
        float qq = w0*(w0*mom[64] + 2.f*(w1*mom[80] + w2*mom[96] + w3*mom[112]))
                 + w1*(w1*mom[128] + 2.f*(w2*mom[144] + w3*mom[160]))
                 + w2*(w2*mom[176] + 2.f*w3*mom[192])
                 + w3*w3*mom[208];
        float var = qq * invM - meanf * meanf;
        float sc  = g1[ci] * rsqrtf(var + BN_EPS);
        w1L[ci] = make_float4(sc*w0, sc*w1, sc*w2, sc*w3);
        c1L[ci] = fmaf(-sc, meanf, be1[ci]);
    }
}

// x2 B-fragment for one position (identical fmaf chain in all passes)
__device__ __forceinline__ void build_xb2(
    float4 f, int q, const float4* w1L, const float* c1L, bf16x8 xb2[2])
{
    #pragma unroll
    for (int h = 0; h < 2; ++h)
      #pragma unroll
      for (int j = 0; j < 8; ++j) {
        int ci = h*32 + q*8 + j;
        float4 w = w1L[ci];
        float x = fmaxf(fmaf(w.x, f.x, fmaf(w.y, f.y, fmaf(w.z, f.z,
                       fmaf(w.w, f.w, c1L[ci])))), 0.f);
        xb2[h][j] = (short)f2bf_bits(x);
      }
}

// ---------------------------------------------------------------------------
// P1: conv2 + stats2 (no y2 materialization).
// ---------------------------------------------------------------------------
__global__ __launch_bounds__(256) void p1_kernel(
    const float4* __restrict__ feats4,
    const float* __restrict__ W1, const float* __restrict__ g1,
    const float* __restrict__ be1, const float* __restrict__ W2,
    const float* __restrict__ mom,
    float* __restrict__ s2S, float* __restrict__ s2Q)
{
    __shared__ float4 w1L[64];
    __shared__ float  c1L[64];
    __shared__ float statS[64], statQ[64];
    const int tid = threadIdx.x;
    const int wid = tid >> 6, l = tid & 63, q = l >> 4, i = l & 15;
    if (tid < 64) { statS[tid] = 0.f; statQ[tid] = 0.f; }
    build_w1L(tid, W1, g1, be1, mom, w1L, c1L);

    bf16x8 a2[4][2];
    #pragma unroll
    for (int t = 0; t < 4; ++t)
      #pragma unroll
      for (int h = 0; h < 2; ++h)
        #pragma unroll
        for (int j = 0; j < 8; ++j)
          a2[t][h][j] = (short)f2bf_bits(W2[(t*16 + i)*64 + h*32 + q*8 + j]);

    float ssum[16], ssq[16];
    #pragma unroll
    for (int s = 0; s < 16; ++s) { ssum[s] = 0.f; ssq[s] = 0.f; }
    __syncthreads();

    for (int r16 = 0; r16 < 16; ++r16) {
        const int row = blockIdx.x * 16 + r16;
        float4 f = feats4[row*64 + wid*16 + i];
        bf16x8 xb2[2];
        build_xb2(f, q, w1L, c1L, xb2);
        #pragma unroll
        for (int t = 0; t < 4; ++t) {
            f32x4 a = (f32x4){0.f,0.f,0.f,0.f};
            a = __builtin_amdgcn_mfma_f32_16x16x32_bf16(a2[t][0], xb2[0], a, 0, 0, 0);
            a = __builtin_amdgcn_mfma_f32_16x16x32_bf16(a2[t][1], xb2[1], a, 0, 0, 0);
            #pragma unroll
            for (int reg = 0; reg < 4; ++reg) {
                float y = a[reg];
                ssum[t*4+reg] += y;
                ssq[t*4+reg]  = fmaf(y, y, ssq[t*4+reg]);
            }
        }
    }
    #pragma unroll
    for (int s = 0; s < 16; ++s) {
        #pragma unroll
        for (int off = 1; off < 16; off <<= 1) {
            ssum[s] += __shfl_xor(ssum[s], off, 64);
            ssq[s]  += __shfl_xor(ssq[s],  off, 64);
        }
    }
    if (i == 0) {
        #pragma unroll
        for (int s = 0; s < 16; ++s) {
            int co = (s >> 2)*16 + q*4 + (s & 3);
            atomicAdd(&statS[co], ssum[s]);
            atomicAdd(&statQ[co], ssq[s]);
        }
    }
    __syncthreads();
    if (tid < 64) { atomicAdd(&s2S[tid], statS[tid]); atomicAdd(&s2Q[tid], statQ[tid]); }
}

// ---------------------------------------------------------------------------
// P2/P3: recompute conv2, feed conv3 via K-permuted W3 fragments.
// Channel permutation: k=(h,q,j) <-> ch = (2h+(j>>2))*16 + q*4 + (j&3),
// which is exactly conv2's C-layout — zero-cost "transpose".
// P2 (FINAL=false): stats3. P3 (FINAL=true): bn3 -> max -> softmax -> out.
// ---------------------------------------------------------------------------
template<bool FINAL>
__global__ __launch_bounds__(256) void p23_kernel(
    const float4* __restrict__ feats4,
    const float* __restrict__ W1, const float* __restrict__ g1,
    const float* __restrict__ be1, const float* __restrict__ W2,
    const float* __restrict__ mom,
    const float* __restrict__ g2, const float* __restrict__ be2,
    const float* __restrict__ W3,
    const float* __restrict__ g3, const float* __restrict__ be3,
    const float* __restrict__ s2S, const float* __restrict__ s2Q,
    float* __restrict__ s3S, float* __restrict__ s3Q,
    const float* __restrict__ p1, float* __restrict__ outp)
{
    __shared__ float4 w1L[64];
    __shared__ float  c1L[64];
    __shared__ float statS[128], statQ[128];   // stats pass / (sc3,sh3 reuse)
    __shared__ float scoreL[2][64];

    const int tid = threadIdx.x;
    const int wid = tid >> 6, l = tid & 63, q = l >> 4, i = l & 15;

    build_w1L(tid, W1, g1, be1, mom, w1L, c1L);
    if (!FINAL) {
        if (tid < 128) { statS[tid] = 0.f; statQ[tid] = 0.f; }
    } else if (tid < 128) {
        float m  = s3S[tid] * (1.0f / MTOT);
        float v  = s3Q[tid] * (1.0f / MTOT) - m * m;
        float sc = g3[tid] * rsqrtf(v + BN_EPS);
        statS[tid] = sc;                      // sc3
        statQ[tid] = fmaf(-sc, m, be3[tid]);  // sh3
    }

    // bn2 consts for the channels this lane holds in conv2 C-layout:
    // s = t*4+reg -> ch = t*16 + q*4 + reg
    float sc2v[16], sh2v[16];
    #pragma unroll
    for (int s = 0; s < 16; ++s) {
        int ch = (s >> 2)*16 + q*4 + (s & 3);
        float m  = s2S[ch] * (1.0f / MTOT);
        float v  = s2Q[ch] * (1.0f / MTOT) - m * m;
        float sc = g2[ch] * rsqrtf(v + BN_EPS);
        sc2v[s] = sc;
        sh2v[s] = fmaf(-sc, m, be2[ch]);
    }
    bf16x8 a2[4][2];
    #pragma unroll
    for (int t = 0; t < 4; ++t)
      #pragma unroll
      for (int h = 0; h < 2; ++h)
        #pragma unroll
        for (int j = 0; j < 8; ++j)
          a2[t][h][j] = (short)f2bf_bits(W2[(t*16 + i)*64 + h*32 + q*8 + j]);
    // W3 A-frags with permuted K gather (absorbs the layout change)
    bf16x8 a3[8][2];
    #pragma unroll
    for (int t = 0; t < 8; ++t)
      #pragma unroll
      for (int h = 0; h < 2; ++h)
        #pragma unroll
        for (int j = 0; j < 8; ++j) {
          int ch = (2*h + (j >> 2))*16 + q*4 + (j & 3);
          a3[t][h][j] = (short)f2bf_bits(W3[(t*16 + i)*64 + ch]);
        }

    float ssum[32], ssq[32];
    if (!FINAL) {
        #pragma unroll
        for (int s = 0; s < 32; ++s) { ssum[s] = 0.f; ssq[s] = 0.f; }
    }
    __syncthreads();

    for (int r16 = 0; r16 < 16; ++r16) {
        const int row = blockIdx.x * 16 + r16;
        float4 f = feats4[row*64 + wid*16 + i];
        bf16x8 xb2[2];
        build_xb2(f, q, w1L, c1L, xb2);
        f32x4 acc2[4];
        #pragma unroll
        for (int t = 0; t < 4; ++t) {
            f32x4 a = (f32x4){0.f,0.f,0.f,0.f};
            a = __builtin_amdgcn_mfma_f32_16x16x32_bf16(a2[t][0], xb2[0], a, 0, 0, 0);
            a = __builtin_amdgcn_mfma_f32_16x16x32_bf16(a2[t][1], xb2[1], a, 0, 0, 0);
            acc2[t] = a;
        }
        // x3 B-frag directly from acc2 (f32 y2, no bf16 round-trip)
        bf16x8 xb3[2];
        #pragma unroll
        for (int h = 0; h < 2; ++h)
          #pragma unroll
          for (int j = 0; j < 8; ++j) {
            int t = 2*h + (j >> 2), reg = j & 3, s = t*4 + reg;
            float x = fmaxf(fmaf(sc2v[s], acc2[t][reg], sh2v[s]), 0.f);
            xb3[h][j] = (short)f2bf_bits(x);
          }

        if (!FINAL) {
            #pragma unroll
            for (int t = 0; t < 8; ++t) {
                f32x4 a = (f32x4){0.f,0.f,0.f,0.f};
                a = __builtin_amdgcn_mfma_f32_16x16x32_bf16(a3[t][0], xb3[0], a, 0, 0, 0);
                a = __builtin_amdgcn_mfma_f32_16x16x32_bf16(a3[t][1], xb3[1], a, 0, 0, 0);
                #pragma unroll
                for (int reg = 0; reg < 4; ++reg) {
                    float y = a[reg];
                    ssum[t*4+reg] += y;
                    ssq[t*4+reg]  = fmaf(y, y, ssq[t*4+reg]);
                }
            }
        } else {
            float mx = -3.4e38f;
            #pragma unroll
            for (int t = 0; t < 8; ++t) {
                f32x4 a = (f32x4){0.f,0.f,0.f,0.f};
                a = __builtin_amdgcn_mfma_f32_16x16x32_bf16(a3[t][0], xb3[0], a, 0, 0, 0);
                a = __builtin_amdgcn_mfma_f32_16x16x32_bf16(a3[t][1], xb3[1], a, 0, 0, 0);
                float4 s4 = *(const float4*)&statS[t*16 + q*4];
                float4 h4 = *(const float4*)&statQ[t*16 + q*4];
                mx = fmaxf(mx, fmaf(s4.x, a[0], h4.x));
                mx = fmaxf(mx, fmaf(s4.y, a[1], h4.y));
                mx = fmaxf(mx, fmaf(s4.z, a[2], h4.z));
                mx = fmaxf(mx, fmaf(s4.w, a[3], h4.w));
            }
            mx = fmaxf(mx, __shfl_xor(mx, 16, 64));
            mx = fmaxf(mx, __shfl_xor(mx, 32, 64));
            mx = fmaxf(mx, 0.f);
            if (q == 0) scoreL[r16 & 1][wid*16 + i] = mx;
            __syncthreads();
            if (wid == 0) {
                float sc = scoreL[r16 & 1][l];
                float m2 = sc;
                #pragma unroll
                for (int off = 1; off < 64; off <<= 1) m2 = fmaxf(m2, __shfl_xor(m2, off, 64));
                float e = __expf(sc - m2);
                float se = e;
                #pragma unroll
                for (int off = 1; off < 64; off <<= 1) se += __shfl_xor(se, off, 64);
                float w = e / se;
                const int bb = row >> 12, n = row & 4095;
                float qx = p1[(size_t)bb*3*N_ + n];
                float qy = p1[(size_t)bb*3*N_ + N_ + n];
                float qz = p1[(size_t)bb*3*N_ + 2*N_ + n];
                float4 f4 = feats4[row*64 + l];
                float ox = w * (f4.x + qx), oy = w * (f4.y + qy), oz = w * (f4.z + qz);
                #pragma unroll
                for (int off = 1; off < 64; off <<= 1) {
                    ox += __shfl_xor(ox, off, 64);
                    oy += __shfl_xor(oy, off, 64);
                    oz += __shfl_xor(oz, off, 64);
                }
                if (l == 0) {
                    outp[bb*3*N_ + 0*N_ + n] = ox;
                    outp[bb*3*N_ + 1*N_ + n] = oy;
                    outp[bb*3*N_ + 2*N_ + n] = oz;
                }
            }
        }
    }

    if (!FINAL) {
        #pragma unroll
        for (int s = 0; s < 32; ++s) {
            #pragma unroll
            for (int off = 1; off < 16; off <<= 1) {
                ssum[s] += __shfl_xor(ssum[s], off, 64);
                ssq[s]  += __shfl_xor(ssq[s],  off, 64);
            }
        }
        if (i == 0) {
            #pragma unroll
            for (int s = 0; s < 32; ++s) {
                int co = (s >> 2)*16 + q*4 + (s & 3);
                atomicAdd(&statS[co], ssum[s]);
                atomicAdd(&statQ[co], ssq[s]);
            }
        }
        __syncthreads();
        if (tid < 128) { atomicAdd(&s3S[tid], statS[tid]); atomicAdd(&s3Q[tid], statQ[tid]); }
    }
}

// ---------------------------------------------------------------------------
extern "C" void kernel_launch(void* const* d_in, const int* in_sizes, int n_in,
                              void* d_out, int out_size, void* d_ws, size_t ws_size,
                              hipStream_t stream)
{
    const float* p1  = (const float*)d_in[0];
    const float* p2  = (const float*)d_in[1];
    // d_in[2] = k (always 32), d_in[3] = t (unused by reference)
    const float* W1  = (const float*)d_in[4];
    const float* g1  = (const float*)d_in[6];
    const float* be1 = (const float*)d_in[7];
    const float* W2  = (const float*)d_in[8];
    const float* g2  = (const float*)d_in[10];
    const float* be2 = (const float*)d_in[11];
    const float* W3  = (const float*)d_in[12];
    const float* g3  = (const float*)d_in[14];
    const float* be3 = (const float*)d_in[15];
    // b1 cancels through bn1 (moment fold); b2/b3 cancel through bn2/bn3.

    char* ws = (char*)d_ws;
    const size_t OFF_FEATS = 4096;
    const size_t NEEDED    = OFF_FEATS + (size_t)MTOT * 4 * 4;   // 16 MB feats only
    if (ws_size < NEEDED) return;  // fail visibly (wrong output) rather than fault

    float* s2S = (float*)(ws + 512);  float* s2Q = (float*)(ws + 768);
    float* s3S = (float*)(ws + 1024); float* s3Q = (float*)(ws + 1536);
    float* mom = (float*)(ws + 2048);            // 14 counters, 64-B stride each
    float* feats = (float*)(ws + OFF_FEATS);

    hipMemsetAsync(ws, 0, 4096, stream);  // zero stats + padded moment counters

    knn_kernel<<<768, 256, 0, stream>>>(p1, p2, feats);
    moments_kernel<<<256, 256, 0, stream>>>((const float4*)feats, mom);
    p1_kernel<<<1024, 256, 0, stream>>>((const float4*)feats, W1, g1, be1, W2,
                                        mom, s2S, s2Q);
    p23_kernel<false><<<1024, 256, 0, stream>>>((const float4*)feats, W1, g1, be1,
                                                W2, mom, g2, be2, W3, g3, be3,
                                                s2S, s2Q, s3S, s3Q, nullptr, nullptr);
    p23_kernel<true><<<1024, 256, 0, stream>>>((const float4*)feats, W1, g1, be1,
                                               W2, mom, g2, be2, W3, g3, be3,
                                               s2S, s2Q, s3S, s3Q, p1,
                                               (float*)d_out);
}